// Round 1
// 785.968 us; speedup vs baseline: 1.0794x; 1.0794x over previous
//
#include <hip/hip_runtime.h>

#define SLEN 1024
#define NBATCH 32
#define NHEADS 4
#define HDIM 32
#define EMB 128
// 1032*2 = 2064 B per LDS e-row: 16B-aligned, and 2064/4 = 516 ≡ 4 (mod 32)
// -> row-parallel LDS access is <=2-way bank conflict (1040 gave 4..8-way).
#define LSTRIDE 1032

typedef short short8 __attribute__((ext_vector_type(8)));
typedef short short4v __attribute__((ext_vector_type(4)));
typedef float floatx4 __attribute__((ext_vector_type(4)));
typedef int   intx4  __attribute__((ext_vector_type(4)));

__device__ __forceinline__ unsigned short f2bf(float f) {
    unsigned u = __float_as_uint(f);
    u += 0x7fffu + ((u >> 16) & 1u);   // round-to-nearest-even
    return (unsigned short)(u >> 16);
}
__device__ __forceinline__ float bf2f(unsigned short h) {
    return __uint_as_float(((unsigned)h) << 16);
}

// ---------------------------------------------------------------------------
// Kernel 1: q/k/v head projections (fp32 -> bf16 via MFMA), Wo -> bf16.
//   qb, kb : [N,H,S,32] bf16
//   vt     : [N,H,32,S] bf16 (transposed so PV B-frags are 16B contiguous)
//   Wq folded with 1/sqrt(128).
// ---------------------------------------------------------------------------
__global__ __launch_bounds__(256) void proj_kernel(
    const float* __restrict__ vals, const float* __restrict__ keys,
    const float* __restrict__ qrys,
    const float* __restrict__ Wv, const float* __restrict__ Wk,
    const float* __restrict__ Wq, const float* __restrict__ Wo,
    unsigned short* __restrict__ qb, unsigned short* __restrict__ kb,
    unsigned short* __restrict__ vt, unsigned short* __restrict__ wo_bf)
{
    int b = blockIdx.x;
    int tid = threadIdx.x;
    if (b == 512) {  // Wo fp32 -> bf16 (128x128)
        #pragma unroll
        for (int i = 0; i < 64; ++i) {
            int idx = tid + (i << 8);
            wo_bf[idx] = f2bf(Wo[idx]);
        }
        return;
    }
    int n = b >> 4;
    int s0 = (b & 15) << 6;           // 64 rows per block
    int wave = tid >> 6, lane = tid & 63;
    int quad = lane >> 4, l16 = lane & 15;
    int srow = s0 + (wave << 4);      // this wave's 16 rows

    // B-fragments: B[k=j][n=d] = W[d][j]; half 0: d=l16, half 1: d=16+l16
    short8 bw[3][2];
    const float* Ws[3] = { Wv, Wk, Wq };
    const float scal[3] = { 1.0f, 1.0f, 0.08838834764831845f }; // 1/sqrt(128) folded into Wq
    #pragma unroll
    for (int t = 0; t < 3; ++t) {
        float s = scal[t];
        #pragma unroll
        for (int hh = 0; hh < 2; ++hh) {
            const float* wp = Ws[t] + (hh * 16 + l16) * 32 + quad * 8;
            float4 w0 = *(const float4*)wp;
            float4 w1 = *(const float4*)(wp + 4);
            short8 r;
            r[0] = (short)f2bf(w0.x * s); r[1] = (short)f2bf(w0.y * s);
            r[2] = (short)f2bf(w0.z * s); r[3] = (short)f2bf(w0.w * s);
            r[4] = (short)f2bf(w1.x * s); r[5] = (short)f2bf(w1.y * s);
            r[6] = (short)f2bf(w1.z * s); r[7] = (short)f2bf(w1.w * s);
            bw[t][hh] = r;
        }
    }

    const float* srcs[3] = { vals, keys, qrys };
    #pragma unroll
    for (int t = 0; t < 3; ++t) {
        const float* src = srcs[t];
        #pragma unroll
        for (int h = 0; h < NHEADS; ++h) {
            size_t nh = (size_t)(n * NHEADS + h);
            const float* xp = src + ((size_t)(n * SLEN + srow + l16) * EMB + h * HDIM + quad * 8);
            float4 x0 = *(const float4*)xp;
            float4 x1 = *(const float4*)(xp + 4);
            short8 a;
            a[0] = (short)f2bf(x0.x); a[1] = (short)f2bf(x0.y);
            a[2] = (short)f2bf(x0.z); a[3] = (short)f2bf(x0.w);
            a[4] = (short)f2bf(x1.x); a[5] = (short)f2bf(x1.y);
            a[6] = (short)f2bf(x1.z); a[7] = (short)f2bf(x1.w);
            floatx4 c0 = {0.f, 0.f, 0.f, 0.f};
            floatx4 c1 = {0.f, 0.f, 0.f, 0.f};
            c0 = __builtin_amdgcn_mfma_f32_16x16x32_bf16(a, bw[t][0], c0, 0, 0, 0);
            c1 = __builtin_amdgcn_mfma_f32_16x16x32_bf16(a, bw[t][1], c1, 0, 0, 0);
            if (t == 0) {
                short4v p0, p1;
                p0[0] = (short)f2bf(c0[0]); p0[1] = (short)f2bf(c0[1]);
                p0[2] = (short)f2bf(c0[2]); p0[3] = (short)f2bf(c0[3]);
                p1[0] = (short)f2bf(c1[0]); p1[1] = (short)f2bf(c1[1]);
                p1[2] = (short)f2bf(c1[2]); p1[3] = (short)f2bf(c1[3]);
                *(short4v*)(vt + (nh * HDIM + l16) * SLEN + srow + quad * 4) = p0;
                *(short4v*)(vt + (nh * HDIM + 16 + l16) * SLEN + srow + quad * 4) = p1;
            } else {
                unsigned short* dst = (t == 1 ? kb : qb) +
                    (nh * SLEN + srow + quad * 4) * HDIM;
                #pragma unroll
                for (int r = 0; r < 4; ++r) {
                    dst[r * HDIM + l16]      = f2bf(c0[r]);
                    dst[r * HDIM + 16 + l16] = f2bf(c1[r]);
                }
            }
        }
    }
}

// ---------------------------------------------------------------------------
// Kernel 2 (register-softmax rewrite): per (n, 16 q-rows), loop 4 heads.
// Swapped QK^T: mfma(K_frag, Q_frag) -> C col = q-row (l16), row = k-index
// (quad*4+r). Each lane holds 64 logits of ONE q-row in regs (c[16] x4).
// Mask/max/exp/weight-write all on registers; only unnormalized e goes to
// LDS (bf16, packed 8B stores) for the PV A-fragments.
// ---------------------------------------------------------------------------
__global__ __launch_bounds__(256, 3) void attn_kernel(
    const unsigned short* __restrict__ qb, const unsigned short* __restrict__ kb,
    const unsigned short* __restrict__ vt, const int* __restrict__ mask,
    float* __restrict__ wout, unsigned short* __restrict__ attnv)
{
    __shared__ unsigned short eb[16 * LSTRIDE];        // e (bf16), [q=16][k=1024]
    __shared__ unsigned long long mb[16][17];          // mask bits (padded rows)
    __shared__ float partial[4][16][32];               // per-wave PV partials
    __shared__ __align__(16) float redmax[16][4];
    __shared__ __align__(16) float redsum[16][4];

    int bid = blockIdx.x;
    int n = bid >> 6;            // 64 row-blocks per batch
    int r0 = (bid & 63) << 4;    // 16 query rows per block
    int tid = threadIdx.x;
    int wave = tid >> 6, lane = tid & 63;
    int quad = lane >> 4, l16 = lane & 15;
    int srow = tid >> 4, c16 = tid & 15;

    // ---- mask bits: coalesced read once per block, staged to LDS ----
    // producer bit (i*8+j) of mb[srow][c16]  <->  col (c16+16*i)*8 + j
    {
        unsigned long long mbits = 0ull;
        const int* mrow = mask + (size_t)(n * SLEN + r0 + srow) * SLEN;
        #pragma unroll
        for (int i = 0; i < 8; ++i) {
            int cb = (c16 + (i << 4)) << 3;
            intx4 a  = __builtin_nontemporal_load((const intx4*)(mrow + cb));
            intx4 bq = __builtin_nontemporal_load((const intx4*)(mrow + cb + 4));
            unsigned bits = 0;
            bits |= (unsigned)(a[0] != 0);
            bits |= (unsigned)(a[1] != 0) << 1;
            bits |= (unsigned)(a[2] != 0) << 2;
            bits |= (unsigned)(a[3] != 0) << 3;
            bits |= (unsigned)(bq[0] != 0) << 4;
            bits |= (unsigned)(bq[1] != 0) << 5;
            bits |= (unsigned)(bq[2] != 0) << 6;
            bits |= (unsigned)(bq[3] != 0) << 7;
            mbits |= (unsigned long long)bits << (i * 8);
        }
        mb[srow][c16] = mbits;
    }
    __syncthreads();

    // ---- per-lane mask for swapped layout: q=l16, k = wave*256+t*16+quad*4+r,
    //      stored at lmask bit (4t+r).
    //      k -> producer chunk c16' = (2t + (quad>>1)) & 15,
    //           bit = (2*wave + (t>>3))*8 + (quad&1)*4 + r       (verified)
    unsigned long long lmask = 0ull;
    {
        int qh = quad >> 1, ql = quad & 1;
        int shbase = (wave << 4) + (ql << 2);   // 2*wave*8 + ql*4
        #pragma unroll
        for (int t = 0; t < 16; ++t) {
            unsigned long long ch = mb[l16][((t << 1) + qh) & 15];
            unsigned long long nib = (ch >> (shbase + ((t >> 3) << 3))) & 0xFull;
            lmask |= nib << (t << 2);
        }
    }

    for (int h = 0; h < NHEADS; ++h) {
        size_t nh = (size_t)(n * NHEADS + h);

        // Q as the B-operand (same 16B frag load as before)
        short8 qfrag = *(const short8*)(qb + (nh * SLEN + r0 + l16) * HDIM + quad * 8);
        const unsigned short* kbase = kb + (nh * SLEN + (wave << 8)) * HDIM;

        // ---- QK^T into registers, fused mask + running max ----
        floatx4 c[16];
        float mx = -3.0e38f;
        #pragma unroll
        for (int t = 0; t < 16; ++t) {
            short8 kfrag = *(const short8*)(kbase + (size_t)((t << 4) + l16) * HDIM + quad * 8);
            floatx4 acc = {0.f, 0.f, 0.f, 0.f};
            acc = __builtin_amdgcn_mfma_f32_16x16x32_bf16(kfrag, qfrag, acc, 0, 0, 0);
            unsigned nb = (unsigned)(lmask >> (t << 2)) & 15u;
            #pragma unroll
            for (int r = 0; r < 4; ++r) {
                float x = ((nb >> r) & 1u) ? acc[r] : -1e20f;
                acc[r] = x;
                mx = fmaxf(mx, x);
            }
            c[t] = acc;
        }
        // row max: 4 lanes/row within wave, then 4 waves via LDS
        mx = fmaxf(mx, __shfl_xor(mx, 16));
        mx = fmaxf(mx, __shfl_xor(mx, 32));
        if (quad == 0) redmax[l16][wave] = mx;
        __syncthreads();                                   // B1
        {
            floatx4 mv = *(const floatx4*)&redmax[l16][0];
            mx = fmaxf(fmaxf(mv[0], mv[1]), fmaxf(mv[2], mv[3]));
        }

        // ---- exp in registers; e (bf16) to LDS once for PV ----
        float sum = 0.f;
        unsigned short* erow = eb + l16 * LSTRIDE + (wave << 8);
        #pragma unroll
        for (int t = 0; t < 16; ++t) {
            floatx4 cc = c[t];
            float e0 = __expf(cc[0] - mx);
            float e1 = __expf(cc[1] - mx);
            float e2 = __expf(cc[2] - mx);
            float e3 = __expf(cc[3] - mx);
            sum += (e0 + e1) + (e2 + e3);
            cc[0] = e0; cc[1] = e1; cc[2] = e2; cc[3] = e3;
            c[t] = cc;
            short4v p;
            p[0] = (short)f2bf(e0); p[1] = (short)f2bf(e1);
            p[2] = (short)f2bf(e2); p[3] = (short)f2bf(e3);
            *(short4v*)(erow + (t << 4) + (quad << 2)) = p;
        }
        sum += __shfl_xor(sum, 16);
        sum += __shfl_xor(sum, 32);
        if (quad == 0) redsum[l16][wave] = sum;
        __syncthreads();                                   // B2 (e + redsum visible)
        float inv;
        {
            floatx4 sv = *(const floatx4*)&redsum[l16][0];
            inv = 1.0f / ((sv[0] + sv[1]) + (sv[2] + sv[3]));
        }

        // ---- normalized weights straight from registers (nontemporal f32) ----
        float* wrow = wout + (nh * SLEN + r0 + l16) * SLEN + (wave << 8);
        #pragma unroll
        for (int t = 0; t < 16; ++t) {
            floatx4 wv;
            wv[0] = c[t][0] * inv; wv[1] = c[t][1] * inv;
            wv[2] = c[t][2] * inv; wv[3] = c[t][3] * inv;
            __builtin_nontemporal_store(wv, (floatx4*)(wrow + (t << 4) + (quad << 2)));
        }

        // ---- PV: out[m][d] = inv[m] * sum_l e[m][l] * V[l][d] ----
        floatx4 acc0 = {0.f, 0.f, 0.f, 0.f}, acc1 = {0.f, 0.f, 0.f, 0.f};
        const unsigned short* vbase = vt + nh * HDIM * SLEN;
        #pragma unroll
        for (int i = 0; i < 8; ++i) {
            int kt = (wave << 3) + i;   // 32-wide l tile
            short8 a8 = *(const short8*)(eb + l16 * LSTRIDE + (kt << 5) + (quad << 3));
            short8 b0 = *(const short8*)(vbase + (size_t)l16 * SLEN + (kt << 5) + (quad << 3));
            short8 b1 = *(const short8*)(vbase + (size_t)(16 + l16) * SLEN + (kt << 5) + (quad << 3));
            acc0 = __builtin_amdgcn_mfma_f32_16x16x32_bf16(a8, b0, acc0, 0, 0, 0);
            acc1 = __builtin_amdgcn_mfma_f32_16x16x32_bf16(a8, b1, acc1, 0, 0, 0);
        }
        #pragma unroll
        for (int r = 0; r < 4; ++r) {
            partial[wave][quad * 4 + r][l16] = acc0[r];
            partial[wave][quad * 4 + r][16 + l16] = acc1[r];
        }
        __syncthreads();                                   // B3

        // ---- cross-wave reduce + write attnV (bf16) ----
        {
            int m = srow;
            int d0 = c16 << 1;
            float s0 = partial[0][m][d0] + partial[1][m][d0] +
                       partial[2][m][d0] + partial[3][m][d0];
            float s1 = partial[0][m][d0 + 1] + partial[1][m][d0 + 1] +
                       partial[2][m][d0 + 1] + partial[3][m][d0 + 1];
            floatx4 sv = *(const floatx4*)&redsum[m][0];
            float iv = 1.0f / ((sv[0] + sv[1]) + (sv[2] + sv[3]));
            unsigned pk = (unsigned)f2bf(s0 * iv) | ((unsigned)f2bf(s1 * iv) << 16);
            __builtin_nontemporal_store(pk,
                (unsigned*)(attnv + (size_t)(n * SLEN + r0 + m) * EMB + h * HDIM + d0));
        }
        // NOTE: no end-of-head barrier needed: next head's first shared-mem
        // writes (redmax before its B1; eb/partial/redsum after its B1/B2)
        // are ordered behind this head's B3 + the next B1 for all threads.
    }
}

// ---------------------------------------------------------------------------
// Kernel 3: out = attnV @ Wo^T + bo   (M=32768, N=128, K=128, bf16 MFMA)
// ---------------------------------------------------------------------------
__global__ __launch_bounds__(256) void out_kernel(
    const unsigned short* __restrict__ attnv, const unsigned short* __restrict__ wo_bf,
    const float* __restrict__ bo, float* __restrict__ out)
{
    int tid = threadIdx.x;
    int wave = tid >> 6, lane = tid & 63;
    int quad = lane >> 4, l16 = lane & 15;
    int m0 = blockIdx.x * 64 + (wave << 4);

    short8 afr[4];
    const unsigned short* ap = attnv + (size_t)(m0 + l16) * EMB + quad * 8;
    #pragma unroll
    for (int ks = 0; ks < 4; ++ks) afr[ks] = *(const short8*)(ap + ks * 32);

    #pragma unroll
    for (int ct = 0; ct < 8; ++ct) {
        floatx4 c = {0.f, 0.f, 0.f, 0.f};
        const unsigned short* bp = wo_bf + ((ct << 4) + l16) * EMB + quad * 8;
        #pragma unroll
        for (int ks = 0; ks < 4; ++ks) {
            short8 b = *(const short8*)(bp + ks * 32);
            c = __builtin_amdgcn_mfma_f32_16x16x32_bf16(afr[ks], b, c, 0, 0, 0);
        }
        int col = (ct << 4) + l16;
        float bias = bo[col];
        #pragma unroll
        for (int r = 0; r < 4; ++r)
            __builtin_nontemporal_store(c[r] + bias,
                &out[(size_t)(m0 + quad * 4 + r) * EMB + col]);
    }
}

// ---------------------------------------------------------------------------
extern "C" void kernel_launch(void* const* d_in, const int* in_sizes, int n_in,
                              void* d_out, int out_size, void* d_ws, size_t ws_size,
                              hipStream_t stream)
{
    (void)in_sizes; (void)n_in; (void)out_size; (void)ws_size;
    const float* vals = (const float*)d_in[0];
    const float* keys = (const float*)d_in[1];
    const float* qrys = (const float*)d_in[2];
    const int*   mask = (const int*)d_in[3];
    const float* Wv   = (const float*)d_in[4];
    const float* Wk   = (const float*)d_in[5];
    const float* Wq   = (const float*)d_in[6];
    const float* Wo   = (const float*)d_in[7];
    const float* bo   = (const float*)d_in[8];
    float* out = (float*)d_out;

    const size_t NHS = (size_t)NBATCH * NHEADS * SLEN * HDIM;  // 4,194,304
    unsigned short* ws = (unsigned short*)d_ws;
    unsigned short* qb    = ws;
    unsigned short* kbuf  = qb + NHS;
    unsigned short* vt    = kbuf + NHS;
    unsigned short* av    = vt + NHS;                          // [N,S,128] bf16
    unsigned short* wo_bf = av + (size_t)NBATCH * SLEN * EMB;  // [128,128] bf16
    float* wout = out + (size_t)NBATCH * SLEN * EMB;           // weights region of d_out

    hipLaunchKernelGGL(proj_kernel, dim3(513), dim3(256), 0, stream,
                       vals, keys, qrys, Wv, Wk, Wq, Wo, qb, kbuf, vt, wo_bf);
    hipLaunchKernelGGL(attn_kernel, dim3(NBATCH * 64), dim3(256), 0, stream,
                       qb, kbuf, vt, mask, wout, av);
    hipLaunchKernelGGL(out_kernel, dim3((NBATCH * SLEN) / 64), dim3(256), 0, stream,
                       av, wo_bf, bo, out);
}

// Round 3
// 772.960 us; speedup vs baseline: 1.0976x; 1.0168x over previous
//
#include <hip/hip_runtime.h>

#define SLEN 1024
#define NBATCH 32
#define NHEADS 4
#define HDIM 32
#define EMB 128
// 1032*2 = 2064 B per LDS e-row: 16B-aligned, 2064/4 = 516 ≡ 4 (mod 32)
// -> b128 row-parallel reads are 2-way (free), b64 writes <=4-way.
#define LSTRIDE 1032
#define AVS 136   // avls row stride (136*2=272 B ≡ 4 mod 32 banks)

typedef short short8 __attribute__((ext_vector_type(8)));
typedef short short4v __attribute__((ext_vector_type(4)));
typedef float floatx4 __attribute__((ext_vector_type(4)));
typedef int   intx4  __attribute__((ext_vector_type(4)));

__device__ __forceinline__ unsigned short f2bf(float f) {
    unsigned u = __float_as_uint(f);
    u += 0x7fffu + ((u >> 16) & 1u);   // round-to-nearest-even
    return (unsigned short)(u >> 16);
}
__device__ __forceinline__ float bf2f(unsigned short h) {
    return __uint_as_float(((unsigned)h) << 16);
}

// ---------------------------------------------------------------------------
// Kernel 1: q/k/v head projections (fp32 -> bf16 via MFMA), Wo -> bf16.
//   qb, kb : [N,H,S,32] bf16
//   vt     : [N,H,32,S] bf16 (transposed so PV B-frags are 16B contiguous)
//   Wq folded with 1/sqrt(128).
// ---------------------------------------------------------------------------
__global__ __launch_bounds__(256) void proj_kernel(
    const float* __restrict__ vals, const float* __restrict__ keys,
    const float* __restrict__ qrys,
    const float* __restrict__ Wv, const float* __restrict__ Wk,
    const float* __restrict__ Wq, const float* __restrict__ Wo,
    unsigned short* __restrict__ qb, unsigned short* __restrict__ kb,
    unsigned short* __restrict__ vt, unsigned short* __restrict__ wo_bf)
{
    int b = blockIdx.x;
    int tid = threadIdx.x;
    if (b == 512) {  // Wo fp32 -> bf16 (128x128)
        #pragma unroll
        for (int i = 0; i < 64; ++i) {
            int idx = tid + (i << 8);
            wo_bf[idx] = f2bf(Wo[idx]);
        }
        return;
    }
    int n = b >> 4;
    int s0 = (b & 15) << 6;           // 64 rows per block
    int wave = tid >> 6, lane = tid & 63;
    int quad = lane >> 4, l16 = lane & 15;
    int srow = s0 + (wave << 4);      // this wave's 16 rows

    // B-fragments: B[k=j][n=d] = W[d][j]; half 0: d=l16, half 1: d=16+l16
    short8 bw[3][2];
    const float* Ws[3] = { Wv, Wk, Wq };
    const float scal[3] = { 1.0f, 1.0f, 0.08838834764831845f }; // 1/sqrt(128) folded into Wq
    #pragma unroll
    for (int t = 0; t < 3; ++t) {
        float s = scal[t];
        #pragma unroll
        for (int hh = 0; hh < 2; ++hh) {
            const float* wp = Ws[t] + (hh * 16 + l16) * 32 + quad * 8;
            float4 w0 = *(const float4*)wp;
            float4 w1 = *(const float4*)(wp + 4);
            short8 r;
            r[0] = (short)f2bf(w0.x * s); r[1] = (short)f2bf(w0.y * s);
            r[2] = (short)f2bf(w0.z * s); r[3] = (short)f2bf(w0.w * s);
            r[4] = (short)f2bf(w1.x * s); r[5] = (short)f2bf(w1.y * s);
            r[6] = (short)f2bf(w1.z * s); r[7] = (short)f2bf(w1.w * s);
            bw[t][hh] = r;
        }
    }

    const float* srcs[3] = { vals, keys, qrys };
    #pragma unroll
    for (int t = 0; t < 3; ++t) {
        const float* src = srcs[t];
        #pragma unroll
        for (int h = 0; h < NHEADS; ++h) {
            size_t nh = (size_t)(n * NHEADS + h);
            const float* xp = src + ((size_t)(n * SLEN + srow + l16) * EMB + h * HDIM + quad * 8);
            float4 x0 = *(const float4*)xp;
            float4 x1 = *(const float4*)(xp + 4);
            short8 a;
            a[0] = (short)f2bf(x0.x); a[1] = (short)f2bf(x0.y);
            a[2] = (short)f2bf(x0.z); a[3] = (short)f2bf(x0.w);
            a[4] = (short)f2bf(x1.x); a[5] = (short)f2bf(x1.y);
            a[6] = (short)f2bf(x1.z); a[7] = (short)f2bf(x1.w);
            floatx4 c0 = {0.f, 0.f, 0.f, 0.f};
            floatx4 c1 = {0.f, 0.f, 0.f, 0.f};
            c0 = __builtin_amdgcn_mfma_f32_16x16x32_bf16(a, bw[t][0], c0, 0, 0, 0);
            c1 = __builtin_amdgcn_mfma_f32_16x16x32_bf16(a, bw[t][1], c1, 0, 0, 0);
            if (t == 0) {
                short4v p0, p1;
                p0[0] = (short)f2bf(c0[0]); p0[1] = (short)f2bf(c0[1]);
                p0[2] = (short)f2bf(c0[2]); p0[3] = (short)f2bf(c0[3]);
                p1[0] = (short)f2bf(c1[0]); p1[1] = (short)f2bf(c1[1]);
                p1[2] = (short)f2bf(c1[2]); p1[3] = (short)f2bf(c1[3]);
                *(short4v*)(vt + (nh * HDIM + l16) * SLEN + srow + quad * 4) = p0;
                *(short4v*)(vt + (nh * HDIM + 16 + l16) * SLEN + srow + quad * 4) = p1;
            } else {
                unsigned short* dst = (t == 1 ? kb : qb) +
                    (nh * SLEN + srow + quad * 4) * HDIM;
                #pragma unroll
                for (int r = 0; r < 4; ++r) {
                    dst[r * HDIM + l16]      = f2bf(c0[r]);
                    dst[r * HDIM + 16 + l16] = f2bf(c1[r]);
                }
            }
        }
    }
}

// ---------------------------------------------------------------------------
// Kernel 2 (flash-style, fully fused): per (n, 16 q-rows), loop 4 heads.
// Swapped QK^T: mfma(K,Q) -> lane holds 64 logits of ONE q-row in regs.
// Per-WAVE max (no mid-chain barrier): e_w = exp(x - m_w); publish
// (m_w, sum_w); one barrier; weights = e_w * exp(m_w-M)/total.
// PV consumes wave-local e from LDS (same-wave program order, no barrier).
// Epilogue combines per-wave partials with scl[w]=exp(m_w-M)/total and
// stages attnV in LDS; after the head loop the out-projection GEMM
// (attnV @ Wo^T + bo) runs in-block. 2 barriers/head, no out_kernel.
// ---------------------------------------------------------------------------
__global__ __launch_bounds__(256, 3) void attn_kernel(
    const unsigned short* __restrict__ qb, const unsigned short* __restrict__ kb,
    const unsigned short* __restrict__ vt, const int* __restrict__ mask,
    const unsigned short* __restrict__ wo_bf, const float* __restrict__ bo,
    float* __restrict__ wout, float* __restrict__ out)
{
    __shared__ unsigned short eb[16 * LSTRIDE];        // e (bf16), [q=16][k=1024]
    __shared__ unsigned long long mb[16][17];          // mask bits (padded rows)
    __shared__ float partial[4][16][32];               // per-wave PV partials
    __shared__ __align__(16) float redmax[2][16][4];   // per-head-parity
    __shared__ __align__(16) float redsum[2][16][4];
    __shared__ __align__(16) float scl[2][16][4];      // exp(m_w-M)/total
    __shared__ unsigned short avls[16][AVS];           // staged attnV (bf16)

    int bid = blockIdx.x;
    int n = bid >> 6;            // 64 row-blocks per batch
    int r0 = (bid & 63) << 4;    // 16 query rows per block
    int tid = threadIdx.x;
    int wave = tid >> 6, lane = tid & 63;
    int quad = lane >> 4, l16 = lane & 15;
    int srow = tid >> 4, c16 = tid & 15;

    // ---- mask bits: coalesced read once per block, staged to LDS ----
    // producer bit (i*8+j) of mb[srow][c16]  <->  col (c16+16*i)*8 + j
    {
        unsigned long long mbits = 0ull;
        const int* mrow = mask + (size_t)(n * SLEN + r0 + srow) * SLEN;
        #pragma unroll
        for (int i = 0; i < 8; ++i) {
            int cb = (c16 + (i << 4)) << 3;
            intx4 a  = __builtin_nontemporal_load((const intx4*)(mrow + cb));
            intx4 bq = __builtin_nontemporal_load((const intx4*)(mrow + cb + 4));
            unsigned bits = 0;
            bits |= (unsigned)(a[0] != 0);
            bits |= (unsigned)(a[1] != 0) << 1;
            bits |= (unsigned)(a[2] != 0) << 2;
            bits |= (unsigned)(a[3] != 0) << 3;
            bits |= (unsigned)(bq[0] != 0) << 4;
            bits |= (unsigned)(bq[1] != 0) << 5;
            bits |= (unsigned)(bq[2] != 0) << 6;
            bits |= (unsigned)(bq[3] != 0) << 7;
            mbits |= (unsigned long long)bits << (i * 8);
        }
        mb[srow][c16] = mbits;
    }
    __syncthreads();

    // ---- per-lane mask for swapped layout: q=l16, k = wave*256+t*16+quad*4+r,
    //      stored at lmask bit (4t+r). (verified round 1)
    unsigned long long lmask = 0ull;
    {
        int qh = quad >> 1, ql = quad & 1;
        int shbase = (wave << 4) + (ql << 2);   // 2*wave*8 + ql*4
        #pragma unroll
        for (int t = 0; t < 16; ++t) {
            unsigned long long ch = mb[l16][((t << 1) + qh) & 15];
            unsigned long long nib = (ch >> (shbase + ((t >> 3) << 3))) & 0xFull;
            lmask |= nib << (t << 2);
        }
    }

    for (int h = 0; h < NHEADS; ++h) {
        size_t nh = (size_t)(n * NHEADS + h);
        int p = h & 1;

        // Q as the B-operand
        short8 qfrag = *(const short8*)(qb + (nh * SLEN + r0 + l16) * HDIM + quad * 8);
        const unsigned short* kbase = kb + (nh * SLEN + (wave << 8)) * HDIM;

        // ---- QK^T into registers, fused mask + running max ----
        floatx4 c[16];
        float mx = -3.0e38f;
        #pragma unroll
        for (int t = 0; t < 16; ++t) {
            short8 kfrag = *(const short8*)(kbase + (size_t)((t << 4) + l16) * HDIM + quad * 8);
            floatx4 acc = {0.f, 0.f, 0.f, 0.f};
            acc = __builtin_amdgcn_mfma_f32_16x16x32_bf16(kfrag, qfrag, acc, 0, 0, 0);
            unsigned nb = (unsigned)(lmask >> (t << 2)) & 15u;
            #pragma unroll
            for (int r = 0; r < 4; ++r) {
                float x = ((nb >> r) & 1u) ? acc[r] : -1e20f;
                acc[r] = x;
                mx = fmaxf(mx, x);
            }
            c[t] = acc;
        }
        // wave-local row max (4 lanes share row l16 within the wave)
        mx = fmaxf(mx, __shfl_xor(mx, 16));
        mx = fmaxf(mx, __shfl_xor(mx, 32));

        // ---- exp with wave-local max; e (bf16) to wave-local LDS region ----
        float sum = 0.f;
        unsigned short* erow = eb + l16 * LSTRIDE + (wave << 8);
        #pragma unroll
        for (int t = 0; t < 16; ++t) {
            floatx4 cc = c[t];
            float e0 = __expf(cc[0] - mx);
            float e1 = __expf(cc[1] - mx);
            float e2 = __expf(cc[2] - mx);
            float e3 = __expf(cc[3] - mx);
            sum += (e0 + e1) + (e2 + e3);
            cc[0] = e0; cc[1] = e1; cc[2] = e2; cc[3] = e3;
            c[t] = cc;
            short4v pk;
            pk[0] = (short)f2bf(e0); pk[1] = (short)f2bf(e1);
            pk[2] = (short)f2bf(e2); pk[3] = (short)f2bf(e3);
            *(short4v*)(erow + (t << 4) + (quad << 2)) = pk;
        }
        sum += __shfl_xor(sum, 16);
        sum += __shfl_xor(sum, 32);
        if (quad == 0) {
            redmax[p][l16][wave] = mx;
            redsum[p][l16][wave] = sum;
        }
        __syncthreads();                                   // B_a

        // ---- combine per-wave stats; factor for this wave's weights ----
        float factor, inv;
        {
            floatx4 mv = *(const floatx4*)&redmax[p][l16][0];
            floatx4 sv = *(const floatx4*)&redsum[p][l16][0];
            float M = fmaxf(fmaxf(mv[0], mv[1]), fmaxf(mv[2], mv[3]));
            float t0 = sv[0] * __expf(mv[0] - M);
            float t1 = sv[1] * __expf(mv[1] - M);
            float t2 = sv[2] * __expf(mv[2] - M);
            float t3 = sv[3] * __expf(mv[3] - M);
            inv = 1.0f / ((t0 + t1) + (t2 + t3));
            float myscale = __expf(mx - M);
            factor = inv * myscale;
            if (quad == 0) scl[p][l16][wave] = factor;     // for epilogue
        }

        // ---- normalized weights straight from registers (nontemporal f32) ----
        float* wrow = wout + (nh * SLEN + r0 + l16) * SLEN + (wave << 8);
        #pragma unroll
        for (int t = 0; t < 16; ++t) {
            floatx4 wv;
            wv[0] = c[t][0] * factor; wv[1] = c[t][1] * factor;
            wv[2] = c[t][2] * factor; wv[3] = c[t][3] * factor;
            __builtin_nontemporal_store(wv, (floatx4*)(wrow + (t << 4) + (quad << 2)));
        }

        // ---- PV on wave-local e: partial_w[m][d] = sum_l e_w[m][l] V[l][d] ----
        floatx4 acc0 = {0.f, 0.f, 0.f, 0.f}, acc1 = {0.f, 0.f, 0.f, 0.f};
        const unsigned short* vbase = vt + nh * HDIM * SLEN;
        #pragma unroll
        for (int i = 0; i < 8; ++i) {
            int kt = (wave << 3) + i;   // this wave's 32-wide l tiles
            short8 a8 = *(const short8*)(eb + l16 * LSTRIDE + (kt << 5) + (quad << 3));
            short8 b0 = *(const short8*)(vbase + (size_t)l16 * SLEN + (kt << 5) + (quad << 3));
            short8 b1 = *(const short8*)(vbase + (size_t)(16 + l16) * SLEN + (kt << 5) + (quad << 3));
            acc0 = __builtin_amdgcn_mfma_f32_16x16x32_bf16(a8, b0, acc0, 0, 0, 0);
            acc1 = __builtin_amdgcn_mfma_f32_16x16x32_bf16(a8, b1, acc1, 0, 0, 0);
        }
        #pragma unroll
        for (int r = 0; r < 4; ++r) {
            partial[wave][quad * 4 + r][l16] = acc0[r];
            partial[wave][quad * 4 + r][16 + l16] = acc1[r];
        }
        __syncthreads();                                   // B_b

        // ---- cross-wave reduce with per-wave scales -> staged attnV ----
        {
            int m = srow;
            int d0 = c16 << 1;
            floatx4 sc = *(const floatx4*)&scl[p][m][0];
            float s0 = partial[0][m][d0] * sc[0] + partial[1][m][d0] * sc[1] +
                       partial[2][m][d0] * sc[2] + partial[3][m][d0] * sc[3];
            float s1 = partial[0][m][d0 + 1] * sc[0] + partial[1][m][d0 + 1] * sc[1] +
                       partial[2][m][d0 + 1] * sc[2] + partial[3][m][d0 + 1] * sc[3];
            unsigned pk = (unsigned)f2bf(s0) | ((unsigned)f2bf(s1) << 16);
            *(unsigned*)&avls[m][h * HDIM + d0] = pk;
        }
        // next head: redmax/redsum/scl are parity-buffered; partial writes
        // happen only after next B_a; eb is wave-local -> no tail barrier.
    }
    __syncthreads();                                       // avls complete

    // ---- out-projection: out[16 rows] = attnV @ Wo^T + bo (in-block) ----
    {
        short8 afr[4];
        const unsigned short* ap = &avls[l16][quad * 8];
        #pragma unroll
        for (int ks = 0; ks < 4; ++ks) afr[ks] = *(const short8*)(ap + ks * 32);

        #pragma unroll
        for (int cc = 0; cc < 2; ++cc) {
            int ct = (wave << 1) + cc;
            floatx4 acc = {0.f, 0.f, 0.f, 0.f};
            const unsigned short* bp = wo_bf + ((ct << 4) + l16) * EMB + quad * 8;
            #pragma unroll
            for (int ks = 0; ks < 4; ++ks) {
                short8 b8 = *(const short8*)(bp + ks * 32);
                acc = __builtin_amdgcn_mfma_f32_16x16x32_bf16(afr[ks], b8, acc, 0, 0, 0);
            }
            int col = (ct << 4) + l16;
            float bias = bo[col];
            #pragma unroll
            for (int r = 0; r < 4; ++r)
                __builtin_nontemporal_store(acc[r] + bias,
                    &out[(size_t)(n * SLEN + r0 + quad * 4 + r) * EMB + col]);
        }
    }
}

// ---------------------------------------------------------------------------
extern "C" void kernel_launch(void* const* d_in, const int* in_sizes, int n_in,
                              void* d_out, int out_size, void* d_ws, size_t ws_size,
                              hipStream_t stream)
{
    (void)in_sizes; (void)n_in; (void)out_size; (void)ws_size;
    const float* vals = (const float*)d_in[0];
    const float* keys = (const float*)d_in[1];
    const float* qrys = (const float*)d_in[2];
    const int*   mask = (const int*)d_in[3];
    const float* Wv   = (const float*)d_in[4];
    const float* Wk   = (const float*)d_in[5];
    const float* Wq   = (const float*)d_in[6];
    const float* Wo   = (const float*)d_in[7];
    const float* bo   = (const float*)d_in[8];
    float* out = (float*)d_out;

    const size_t NHS = (size_t)NBATCH * NHEADS * SLEN * HDIM;  // 4,194,304
    unsigned short* ws = (unsigned short*)d_ws;
    unsigned short* qb    = ws;
    unsigned short* kbuf  = qb + NHS;
    unsigned short* vt    = kbuf + NHS;
    unsigned short* wo_bf = vt + NHS;                          // [128,128] bf16
    float* wout = out + (size_t)NBATCH * SLEN * EMB;           // weights region of d_out

    hipLaunchKernelGGL(proj_kernel, dim3(513), dim3(256), 0, stream,
                       vals, keys, qrys, Wv, Wk, Wq, Wo, qb, kbuf, vt, wo_bf);
    hipLaunchKernelGGL(attn_kernel, dim3(NBATCH * 64), dim3(256), 0, stream,
                       qb, kbuf, vt, mask, wo_bf, bo, wout, out);
}